// Round 13
// baseline (206.211 us; speedup 1.0000x reference)
//
#include <hip/hip_runtime.h>
#include <hip/hip_bf16.h>

typedef __attribute__((ext_vector_type(4))) float f32x4;
typedef __attribute__((ext_vector_type(8))) short s16x8;

constexpr int NN   = 8192;
constexpr int KIN  = 512;
constexpr int KOUT = 128;

constexpr int RBK  = 128;             // rows per block
constexpr int JC   = 4;               // column chunks
constexpr int JLEN = NN / JC;         // 2048
constexpr int SGO  = 64;              // cols per stage
constexpr int NS   = JLEN / SGO;      // 32 stages
// LDS map (48 KB): slab0 @0 (16KB: 128 rows x 128B), slab1 @16384, P @32768 + w*2048 (16 x 128B)
constexpr int SLABSZ = 16384;
constexpr int PBASE  = 32768;

__device__ __forceinline__ ushort f2bf(float x) {
    union { float f; unsigned u; } v; v.f = x;
    unsigned r = (v.u + 0x7fffu + ((v.u >> 16) & 1u)) >> 16;
    return (ushort)r;
}

__device__ __forceinline__ void gload_lds16(const void* g, void* l) {
    __builtin_amdgcn_global_load_lds((const __attribute__((address_space(1))) void*)g,
                                     (__attribute__((address_space(3))) void*)l, 16, 0, 0);
}

// ---------------- Kernel A: h = input @ W ; hT(bf16), s, t ----------------
__global__ __launch_bounds__(256) void kA(const float* __restrict__ inp,
                                          const float* __restrict__ W,
                                          const float* __restrict__ a_s,
                                          const float* __restrict__ a_n,
                                          ushort* __restrict__ hT,
                                          float* __restrict__ s_out,
                                          float* __restrict__ t_out) {
    __shared__ float smem[16 * 512];
    const int t = threadIdx.x;
    const int rbase = blockIdx.x * 16;

#pragma unroll
    for (int it = 0; it < 8; ++it) {
        int idx = it * 256 + t;
        int r = idx >> 7;
        int c4 = (idx & 127) << 2;
        *(f32x4*)(&smem[r * 512 + c4]) =
            *(const f32x4*)(inp + (size_t)(rbase + r) * KIN + c4);
    }
    __syncthreads();

    const int c0 = (t & 31) * 4;
    const int rg = (t >> 5) * 2;
    float acc[2][4] = {};
#pragma unroll 4
    for (int k = 0; k < KIN; ++k) {
        f32x4 w4 = *(const f32x4*)(W + (size_t)k * KOUT + c0);
        float a0 = smem[(rg + 0) * 512 + k];
        float a1 = smem[(rg + 1) * 512 + k];
#pragma unroll
        for (int cc = 0; cc < 4; ++cc) {
            acc[0][cc] += a0 * w4[cc];
            acc[1][cc] += a1 * w4[cc];
        }
    }
    __syncthreads();

    float* h_lds = smem;                        // [16][128]
#pragma unroll
    for (int rr = 0; rr < 2; ++rr) {
        f32x4 v = {acc[rr][0], acc[rr][1], acc[rr][2], acc[rr][3]};
        *(f32x4*)(&h_lds[(rg + rr) * 128 + c0]) = v;
    }
    __syncthreads();

    {
        const int col = t >> 1;
        const int r0 = (t & 1) * 8;
        ushort tmp[8];
#pragma unroll
        for (int rr = 0; rr < 8; ++rr) tmp[rr] = f2bf(h_lds[(r0 + rr) * 128 + col]);
        *(f32x4*)(hT + (size_t)col * NN + rbase + r0) = *(f32x4*)&tmp[0];
    }

    {
        const int w = t >> 6, lane = t & 63;
        float as1 = a_s[lane], as2 = a_s[64 + lane];
        float an1 = a_n[lane], an2 = a_n[64 + lane];
#pragma unroll
        for (int rr = 0; rr < 4; ++rr) {
            int row = w * 4 + rr;
            float h1 = h_lds[row * 128 + lane];
            float h2 = h_lds[row * 128 + 64 + lane];
            float ps = h1 * as1 + h2 * as2;
            float pt = h1 * an1 + h2 * an2;
#pragma unroll
            for (int off = 32; off; off >>= 1) {
                ps += __shfl_xor(ps, off);
                pt += __shfl_xor(pt, off);
            }
            if (lane == 0) {
                s_out[rbase + row] = ps;
                t_out[rbase + row] = pt;
            }
        }
    }
}

// ---------------- Kernel H: kG geometry + kF contiguous loads + per-wave P transpose ----------------
// grid 256 = 64 rowblocks x 4 jc. Block: 128 rows (8 waves x 16) x 2048 cols. 1 block/CU.
// Stage (64 cols): M/adj loaded CONTIGUOUSLY (instr = 4 rows x 256B), exp computed by the
// loading lane, P transposed through per-wave LDS tile (intra-wave, no barrier), A-frags +
// B-frags (hT slab, DMA dbuf) -> MFMA. ONE barrier per stage. All swizzles XOR-involutions.
__global__ __launch_bounds__(512, 1) void kH(const float* __restrict__ Mmat,
                                             const float* __restrict__ adjm,
                                             const ushort* __restrict__ hT,
                                             const float* __restrict__ s_in,
                                             const float* __restrict__ t_in,
                                             float* __restrict__ o_part,
                                             float* __restrict__ l_part) {
    __shared__ __align__(16) char LDS[49152];

    const int tid = threadIdx.x;
    const int w = tid >> 6;              // 0..7
    const int l = tid & 63;
    const int lrow = l & 15;             // MFMA A-row
    const int kgrp = l >> 4;             // MFMA k-group
    const int rb = blockIdx.x >> 2;
    const int jc = blockIdx.x & 3;
    const int j0 = jc * JLEN;
    const int row0 = rb * RBK;
    const int PH = (int)((blockIdx.x * 5u) & (unsigned)(NS - 1));
    const int POFF = PBASE + w * 2048;

    // producer: lane covers row (l>>4) of each 4-row group q, cols (l&15)*4..+3
    float sreg[4];
#pragma unroll
    for (int q = 0; q < 4; ++q) sreg[q] = s_in[row0 + w * 16 + q * 4 + (l >> 4)];
    float lsum4[4] = {0.f, 0.f, 0.f, 0.f};

    const float* Mq = Mmat + (size_t)(row0 + w * 16 + (l >> 4)) * NN + j0 + (l & 15) * 4;
    const float* Aq = adjm + (size_t)(row0 + w * 16 + (l >> 4)) * NN + j0 + (l & 15) * 4;
    const float* tq = t_in + j0 + (l & 15) * 4;

    // hT slab DMA: instr q2 covers 8 rows x 128B; pre-swizzled src chunk (rule #21)
    const ushort* hq[2];
#pragma unroll
    for (int q2 = 0; q2 < 2; ++q2) {
        int r = w * 16 + q2 * 8 + (l >> 3);
        int sc = ((l & 7) ^ (r & 7)) * 8;            // 16B chunk, swizzled
        hq[q2] = hT + (size_t)r * NN + j0 + sc;
    }

    f32x4 acc[8];
#pragma unroll
    for (int ct = 0; ct < 8; ++ct) acc[ct] = (f32x4){0.f, 0.f, 0.f, 0.f};

    f32x4 Mr[4], Ar[4], tr;

#define DMA_HT(P, SL)                                                            \
    _Pragma("unroll") for (int q2 = 0; q2 < 2; ++q2)                             \
        gload_lds16(hq[q2] + (size_t)(P) * SGO,                                  \
                    LDS + (SL) * SLABSZ + (w * 16 + q2 * 8) * 128);

#define LDG(P)                                                                   \
    _Pragma("unroll") for (int q = 0; q < 4; ++q) {                              \
        Mr[q] = *(const f32x4*)(Mq + (size_t)q * 4 * NN + (size_t)(P) * SGO);    \
        Ar[q] = *(const f32x4*)(Aq + (size_t)q * 4 * NN + (size_t)(P) * SGO);    \
    }                                                                            \
    tr = *(const f32x4*)(tq + (size_t)(P) * SGO);

// compute P(stage) from regs, write to per-wave P tile, reload regs for stage PN
#define EXPW_RELOAD(PN)                                                          \
    {                                                                            \
        _Pragma("unroll") for (int q = 0; q < 4; ++q) {                          \
            const int r = q * 4 + (l >> 4);                                      \
            float pv[4];                                                         \
            _Pragma("unroll") for (int e = 0; e < 4; ++e) {                      \
                float x = (sreg[q] + tr[e]) * Mr[q][e];                          \
                x = fmaxf(x, 0.2f * x);                                          \
                float p = __expf(x) * Ar[q][e];      /* adj is exactly 0/1 */    \
                lsum4[q] += p;                                                   \
                pv[e] = p;                                                       \
            }                                                                    \
            uint2 u;                                                             \
            u.x = (unsigned)f2bf(pv[0]) | ((unsigned)f2bf(pv[1]) << 16);         \
            u.y = (unsigned)f2bf(pv[2]) | ((unsigned)f2bf(pv[3]) << 16);         \
            *(uint2*)(LDS + POFF + r * 128 + (((l & 15) * 8) ^ ((r & 7) << 4))) = u; \
            Mr[q] = *(const f32x4*)(Mq + (size_t)q * 4 * NN + (size_t)(PN) * SGO);   \
            Ar[q] = *(const f32x4*)(Aq + (size_t)q * 4 * NN + (size_t)(PN) * SGO);   \
        }                                                                        \
        tr = *(const f32x4*)(tq + (size_t)(PN) * SGO);                           \
    }

#define KSTEP(K, SL)                                                             \
    {                                                                            \
        s16x8 af = *(const s16x8*)(LDS + POFF + lrow * 128 +                     \
                                   ((((K) * 4 + kgrp) * 16) ^ ((lrow & 7) << 4))); \
        _Pragma("unroll") for (int ct = 0; ct < 8; ++ct) {                       \
            const int brow = ct * 16 + lrow;                                     \
            s16x8 bf = *(const s16x8*)(LDS + (SL) * SLABSZ + brow * 128 +        \
                                       ((((K) * 4 + kgrp) * 16) ^ ((lrow & 7) << 4))); \
            acc[ct] = __builtin_amdgcn_mfma_f32_16x16x32_bf16(af, bf, acc[ct], 0, 0, 0); \
        }                                                                        \
    }

    // prologue: stage PH -> slab0 + regs
    DMA_HT(PH, 0)
    LDG(PH)

#pragma unroll 1
    for (int s = 0; s < NS; ++s) {
        const int sl = s & 1;
        const int pn = (s + 1 + PH) & (NS - 1);     // wraps to dup at tail (harmless)
        asm volatile("s_waitcnt vmcnt(0)" ::: "memory");   // regs(s) + own DMA(s) landed
        __builtin_amdgcn_s_barrier();                      // all waves done with slab[sl^1]
        asm volatile("" ::: "memory");
        DMA_HT(pn, sl ^ 1)                                 // prefetch next slab (safe now)
        EXPW_RELOAD(pn)                                    // P(s) -> LDS; refill regs(s+1)
        KSTEP(0, sl)
        KSTEP(1, sl)
    }
#undef DMA_HT
#undef LDG
#undef EXPW_RELOAD
#undef KSTEP

    // denominator partials: reduce lsum4[q] over the 16 lanes sharing each row
#pragma unroll
    for (int q = 0; q < 4; ++q) {
        float v = lsum4[q];
#pragma unroll
        for (int off = 1; off < 16; off <<= 1) v += __shfl_xor(v, off);
        if ((l & 15) == 0)
            l_part[(size_t)jc * NN + row0 + w * 16 + q * 4 + (l >> 4)] = v;
    }

    // o partials (D layout: row=(lane>>4)*4+reg, col=lane&15)
    float* op = o_part + (size_t)jc * NN * KOUT;
#pragma unroll
    for (int ct = 0; ct < 8; ++ct) {
#pragma unroll
        for (int r = 0; r < 4; ++r) {
            int gi = row0 + w * 16 + kgrp * 4 + r;
            int col = ct * 16 + lrow;
            op[(size_t)gi * KOUT + col] = acc[ct][r];
        }
    }
}

// ---------------- Kernel C: reduce partials, divide, ELU ----------------
__global__ __launch_bounds__(256) void kC(const float* __restrict__ o_part,
                                          const float* __restrict__ l_part,
                                          float* __restrict__ out) {
    const int idx = blockIdx.x * 256 + threadIdx.x;
    const int i = idx >> 7;
    float osum = 0.f, lsum = 0.f;
#pragma unroll
    for (int p = 0; p < JC; ++p) {
        osum += o_part[(size_t)p * NN * KOUT + idx];
        lsum += l_part[(size_t)p * NN + i];
    }
    float v = osum / lsum;
    out[idx] = v > 0.f ? v : (__expf(v) - 1.f);
}

extern "C" void kernel_launch(void* const* d_in, const int* in_sizes, int n_in,
                              void* d_out, int out_size, void* d_ws, size_t ws_size,
                              hipStream_t stream) {
    const float* inp = (const float*)d_in[0];
    const float* adj = (const float*)d_in[1];
    const float* Mm  = (const float*)d_in[2];
    const float* W   = (const float*)d_in[3];
    const float* a_s = (const float*)d_in[4];
    const float* a_n = (const float*)d_in[5];
    float* out = (float*)d_out;

    char* ws = (char*)d_ws;
    ushort* hT    = (ushort*)(ws + 0);              //  2 MB   [128][8192] bf16
    float*  s_buf = (float*)(ws + 2097152);         //  32 KB
    float*  t_buf = (float*)(ws + 2129920);         //  32 KB
    float*  l_prt = (float*)(ws + 2162688);         //  128 KB [4][8192]
    float*  o_prt = (float*)(ws + 4194304);         //  16 MB  [4][8192][128]

    hipLaunchKernelGGL(kA, dim3(512), dim3(256), 0, stream, inp, W, a_s, a_n, hT, s_buf, t_buf);
    hipLaunchKernelGGL(kH, dim3(64 * JC), dim3(512), 0, stream, Mm, adj, hT, s_buf, t_buf, o_prt, l_prt);
    hipLaunchKernelGGL(kC, dim3(4096), dim3(256), 0, stream, o_prt, l_prt, out);
}

// Round 14
// 180.612 us; speedup vs baseline: 1.1417x; 1.1417x over previous
//
#include <hip/hip_runtime.h>
#include <hip/hip_bf16.h>

typedef __attribute__((ext_vector_type(4))) float f32x4;
typedef __attribute__((ext_vector_type(8))) short s16x8;

constexpr int NN   = 8192;
constexpr int KIN  = 512;
constexpr int KOUT = 128;

constexpr int RBK  = 128;             // rows per block
constexpr int JC   = 4;               // column chunks
constexpr int JLEN = NN / JC;         // 2048
constexpr int SGO  = 64;              // cols per stage
constexpr int NS   = JLEN / SGO;      // 32 stages
constexpr int SLABSZ = 16384;         // 128 feat-rows x 64 cols bf16
constexpr int PBASE  = 65536;         // P tiles after 4 slabs

__device__ __forceinline__ ushort f2bf(float x) {
    union { float f; unsigned u; } v; v.f = x;
    unsigned r = (v.u + 0x7fffu + ((v.u >> 16) & 1u)) >> 16;
    return (ushort)r;
}

__device__ __forceinline__ void gload_lds16(const void* g, void* l) {
    __builtin_amdgcn_global_load_lds((const __attribute__((address_space(1))) void*)g,
                                     (__attribute__((address_space(3))) void*)l, 16, 0, 0);
}

// ---------------- Kernel A: h = input @ W ; hT(bf16), s, t ----------------
__global__ __launch_bounds__(256) void kA(const float* __restrict__ inp,
                                          const float* __restrict__ W,
                                          const float* __restrict__ a_s,
                                          const float* __restrict__ a_n,
                                          ushort* __restrict__ hT,
                                          float* __restrict__ s_out,
                                          float* __restrict__ t_out) {
    __shared__ float smem[16 * 512];
    const int t = threadIdx.x;
    const int rbase = blockIdx.x * 16;

#pragma unroll
    for (int it = 0; it < 8; ++it) {
        int idx = it * 256 + t;
        int r = idx >> 7;
        int c4 = (idx & 127) << 2;
        *(f32x4*)(&smem[r * 512 + c4]) =
            *(const f32x4*)(inp + (size_t)(rbase + r) * KIN + c4);
    }
    __syncthreads();

    const int c0 = (t & 31) * 4;
    const int rg = (t >> 5) * 2;
    float acc[2][4] = {};
#pragma unroll 4
    for (int k = 0; k < KIN; ++k) {
        f32x4 w4 = *(const f32x4*)(W + (size_t)k * KOUT + c0);
        float a0 = smem[(rg + 0) * 512 + k];
        float a1 = smem[(rg + 1) * 512 + k];
#pragma unroll
        for (int cc = 0; cc < 4; ++cc) {
            acc[0][cc] += a0 * w4[cc];
            acc[1][cc] += a1 * w4[cc];
        }
    }
    __syncthreads();

    float* h_lds = smem;                        // [16][128]
#pragma unroll
    for (int rr = 0; rr < 2; ++rr) {
        f32x4 v = {acc[rr][0], acc[rr][1], acc[rr][2], acc[rr][3]};
        *(f32x4*)(&h_lds[(rg + rr) * 128 + c0]) = v;
    }
    __syncthreads();

    {
        const int col = t >> 1;
        const int r0 = (t & 1) * 8;
        ushort tmp[8];
#pragma unroll
        for (int rr = 0; rr < 8; ++rr) tmp[rr] = f2bf(h_lds[(r0 + rr) * 128 + col]);
        *(f32x4*)(hT + (size_t)col * NN + rbase + r0) = *(f32x4*)&tmp[0];
    }

    {
        const int w = t >> 6, lane = t & 63;
        float as1 = a_s[lane], as2 = a_s[64 + lane];
        float an1 = a_n[lane], an2 = a_n[64 + lane];
#pragma unroll
        for (int rr = 0; rr < 4; ++rr) {
            int row = w * 4 + rr;
            float h1 = h_lds[row * 128 + lane];
            float h2 = h_lds[row * 128 + 64 + lane];
            float ps = h1 * as1 + h2 * as2;
            float pt = h1 * an1 + h2 * an2;
#pragma unroll
            for (int off = 32; off; off >>= 1) {
                ps += __shfl_xor(ps, off);
                pt += __shfl_xor(pt, off);
            }
            if (lane == 0) {
                s_out[rbase + row] = ps;
                t_out[rbase + row] = pt;
            }
        }
    }
}

// ---------------- Kernel I: kH + depth-3 reg pipeline + ring-4 slabs + counted vmcnt ----------------
// grid 256 = 64 rowblocks x 4 jc; 512 threads (8 waves), 1 block/CU.
// Steady state per wave, per stage s: head wait vmcnt(20) retires exactly {LDG(s), DMA(s)};
// barrier; issue DMA(s+2 -> slab (s+2)&3) then LDG(s+3 -> slot (s+3)&3); EXPW(slot s&3);
// 2 KSTEPs vs slab s&3. Outstanding queue is always [L,D,L,D,L] = 31 instrs -> never drains.
__global__ __launch_bounds__(512, 2) void kI(const float* __restrict__ Mmat,
                                             const float* __restrict__ adjm,
                                             const ushort* __restrict__ hT,
                                             const float* __restrict__ s_in,
                                             const float* __restrict__ t_in,
                                             float* __restrict__ o_part,
                                             float* __restrict__ l_part) {
    __shared__ __align__(16) char LDS[81920];

    const int tid = threadIdx.x;
    const int w = tid >> 6;              // 0..7
    const int l = tid & 63;
    const int lrow = l & 15;
    const int kgrp = l >> 4;
    const int rb = blockIdx.x >> 2;
    const int jc = blockIdx.x & 3;
    const int j0 = jc * JLEN;
    const int row0 = rb * RBK;
    const int PH = (int)((blockIdx.x * 5u) & (unsigned)(NS - 1));
    const int POFF = PBASE + w * 2048;

    // phys column stage (clamped dup at tail, then phase-rotated)
#define PCOL(S) ((((S) < NS ? (S) : NS - 1) + PH) & (NS - 1))

    float sreg[4];
#pragma unroll
    for (int q = 0; q < 4; ++q) sreg[q] = s_in[row0 + w * 16 + q * 4 + (l >> 4)];
    float lsum4[4] = {0.f, 0.f, 0.f, 0.f};

    // contiguous producer bases (4-segment per instr): lane covers row (l>>4) of group q, cols (l&15)*4..+3
    const float* Mq = Mmat + (size_t)(row0 + w * 16 + (l >> 4)) * NN + j0 + (l & 15) * 4;
    const float* Aq = adjm + (size_t)(row0 + w * 16 + (l >> 4)) * NN + j0 + (l & 15) * 4;
    const float* tq = t_in + j0 + (l & 15) * 4;

    // hT slab DMA sources (pre-swizzled global, linear LDS dst; kH-verified)
    const ushort* hq[2];
#pragma unroll
    for (int q2 = 0; q2 < 2; ++q2) {
        int r = w * 16 + q2 * 8 + (l >> 3);
        int sc = ((l & 7) ^ (r & 7)) * 8;
        hq[q2] = hT + (size_t)r * NN + j0 + sc;
    }

    f32x4 acc[8];
#pragma unroll
    for (int ct = 0; ct < 8; ++ct) acc[ct] = (f32x4){0.f, 0.f, 0.f, 0.f};

    // 4 named register slots (compile-time indexed only)
    f32x4 Mr0[4], Ar0[4], tr0;
    f32x4 Mr1[4], Ar1[4], tr1;
    f32x4 Mr2[4], Ar2[4], tr2;
    f32x4 Mr3[4], Ar3[4], tr3;

#define DMA_HT(P, SL)                                                            \
    _Pragma("unroll") for (int q2 = 0; q2 < 2; ++q2)                             \
        gload_lds16(hq[q2] + (size_t)(P) * SGO,                                  \
                    LDS + (SL) * SLABSZ + (w * 16 + q2 * 8) * 128);

#define LDG(SL, P)                                                               \
    {                                                                            \
        _Pragma("unroll") for (int q = 0; q < 4; ++q) {                          \
            Mr##SL[q] = *(const f32x4*)(Mq + (size_t)q * 4 * NN + (size_t)(P) * SGO); \
            Ar##SL[q] = *(const f32x4*)(Aq + (size_t)q * 4 * NN + (size_t)(P) * SGO); \
        }                                                                        \
        tr##SL = *(const f32x4*)(tq + (size_t)(P) * SGO);                        \
    }

#define EXPW(SL)                                                                 \
    {                                                                            \
        _Pragma("unroll") for (int q = 0; q < 4; ++q) {                          \
            const int r = q * 4 + (l >> 4);                                      \
            float pv[4];                                                         \
            _Pragma("unroll") for (int e = 0; e < 4; ++e) {                      \
                float x = (sreg[q] + tr##SL[e]) * Mr##SL[q][e];                  \
                x = fmaxf(x, 0.2f * x);                                          \
                float p = __expf(x) * Ar##SL[q][e];   /* adj is exactly 0/1 */   \
                lsum4[q] += p;                                                   \
                pv[e] = p;                                                       \
            }                                                                    \
            uint2 u;                                                             \
            u.x = (unsigned)f2bf(pv[0]) | ((unsigned)f2bf(pv[1]) << 16);         \
            u.y = (unsigned)f2bf(pv[2]) | ((unsigned)f2bf(pv[3]) << 16);         \
            *(uint2*)(LDS + POFF + r * 128 + (((l & 15) * 8) ^ ((r & 7) << 4))) = u; \
        }                                                                        \
    }

#define KSTEP(K, SL)                                                             \
    {                                                                            \
        s16x8 af = *(const s16x8*)(LDS + POFF + lrow * 128 +                     \
                                   ((((K) * 4 + kgrp) * 16) ^ ((lrow & 7) << 4))); \
        _Pragma("unroll") for (int ct = 0; ct < 8; ++ct) {                       \
            const int brow = ct * 16 + lrow;                                     \
            s16x8 bf = *(const s16x8*)(LDS + (SL) * SLABSZ + brow * 128 +        \
                                       ((((K) * 4 + kgrp) * 16) ^ ((lrow & 7) << 4))); \
            acc[ct] = __builtin_amdgcn_mfma_f32_16x16x32_bf16(af, bf, acc[ct], 0, 0, 0); \
        }                                                                        \
    }

// stage C (0..3): wait(20) -> barrier -> DMA(s+2 -> slab D2) -> LDG(slot L3, s+3) -> compute
#define STAGE(C, D2, L3)                                                         \
    {                                                                            \
        const int s_ = s0 + (C);                                                 \
        asm volatile("s_waitcnt vmcnt(20)" ::: "memory");                        \
        __builtin_amdgcn_s_barrier();                                            \
        asm volatile("" ::: "memory");                                           \
        DMA_HT(PCOL(s_ + 2), D2)                                                 \
        LDG(L3, PCOL(s_ + 3))                                                    \
        EXPW(C)                                                                  \
        KSTEP(0, C)                                                              \
        KSTEP(1, C)                                                              \
    }

    // prologue: queue = [L0(9), D0(2), L1(9), D1(2), L2(9)] = 31
    LDG(0, PCOL(0))
    DMA_HT(PCOL(0), 0)
    LDG(1, PCOL(1))
    DMA_HT(PCOL(1), 1)
    LDG(2, PCOL(2))

#pragma unroll 1
    for (int it = 0; it < NS / 4; ++it) {
        const int s0 = it * 4;
        STAGE(0, 2, 3)
        STAGE(1, 3, 0)
        STAGE(2, 0, 1)
        STAGE(3, 1, 2)
    }
#undef STAGE
#undef KSTEP
#undef EXPW
#undef LDG
#undef DMA_HT
#undef PCOL

    // denominator partials: reduce lsum4[q] over the 16 lanes sharing each row
#pragma unroll
    for (int q = 0; q < 4; ++q) {
        float v = lsum4[q];
#pragma unroll
        for (int off = 1; off < 16; off <<= 1) v += __shfl_xor(v, off);
        if ((l & 15) == 0)
            l_part[(size_t)jc * NN + row0 + w * 16 + q * 4 + (l >> 4)] = v;
    }

    // o partials (D layout: row=(lane>>4)*4+reg, col=lane&15)
    float* op = o_part + (size_t)jc * NN * KOUT;
#pragma unroll
    for (int ct = 0; ct < 8; ++ct) {
#pragma unroll
        for (int r = 0; r < 4; ++r) {
            int gi = row0 + w * 16 + kgrp * 4 + r;
            int col = ct * 16 + lrow;
            op[(size_t)gi * KOUT + col] = acc[ct][r];
        }
    }
}

// ---------------- Kernel C: reduce partials, divide, ELU ----------------
__global__ __launch_bounds__(256) void kC(const float* __restrict__ o_part,
                                          const float* __restrict__ l_part,
                                          float* __restrict__ out) {
    const int idx = blockIdx.x * 256 + threadIdx.x;
    const int i = idx >> 7;
    float osum = 0.f, lsum = 0.f;
#pragma unroll
    for (int p = 0; p < JC; ++p) {
        osum += o_part[(size_t)p * NN * KOUT + idx];
        lsum += l_part[(size_t)p * NN + i];
    }
    float v = osum / lsum;
    out[idx] = v > 0.f ? v : (__expf(v) - 1.f);
}

extern "C" void kernel_launch(void* const* d_in, const int* in_sizes, int n_in,
                              void* d_out, int out_size, void* d_ws, size_t ws_size,
                              hipStream_t stream) {
    const float* inp = (const float*)d_in[0];
    const float* adj = (const float*)d_in[1];
    const float* Mm  = (const float*)d_in[2];
    const float* W   = (const float*)d_in[3];
    const float* a_s = (const float*)d_in[4];
    const float* a_n = (const float*)d_in[5];
    float* out = (float*)d_out;

    char* ws = (char*)d_ws;
    ushort* hT    = (ushort*)(ws + 0);              //  2 MB   [128][8192] bf16
    float*  s_buf = (float*)(ws + 2097152);         //  32 KB
    float*  t_buf = (float*)(ws + 2129920);         //  32 KB
    float*  l_prt = (float*)(ws + 2162688);         //  128 KB [4][8192]
    float*  o_prt = (float*)(ws + 4194304);         //  16 MB  [4][8192][128]

    hipLaunchKernelGGL(kA, dim3(512), dim3(256), 0, stream, inp, W, a_s, a_n, hT, s_buf, t_buf);
    hipLaunchKernelGGL(kI, dim3(64 * JC), dim3(512), 0, stream, Mm, adj, hT, s_buf, t_buf, o_prt, l_prt);
    hipLaunchKernelGGL(kC, dim3(4096), dim3(256), 0, stream, o_prt, l_prt, out);
}